// Round 5
// baseline (234.306 us; speedup 1.0000x reference)
//
#include <hip/hip_runtime.h>
#include <math.h>

#define NB 8            // batch
#define NPIX 262144     // 512*512
#define BPSAMP 64       // blocks per sample
#define NBLK (NB * BPSAMP)   // 512 blocks; capacity 1024 (4/CU via launch_bounds) => all co-resident, 2x margin
#define TPB 256
#define PPT 16          // pixels per thread (values live in registers)
#define PPB (TPB * PPT) // 4096 pixels per block
#define NBINS 1024      // level-1 bins: bits>>21 of a positive float is always < 1024
#define BPT (NBINS / TPB)    // 4 bins per thread in selection
#define NBINS2 256      // level-2 sub-bins: (bits>>13)&255
#define EPS2 1e-12f

#define F4E(v,j) (((const float*)&(v))[j])
#define I4E(v,j) (((const int*)&(v))[j])

struct Sel { unsigned b1, rem, k; };

__device__ __forceinline__ void pixel_vals(float a, float p,
                                           float i0, float i1, float i2,
                                           float f0, float f1, float f2,
                                           float g0, float g1, float g2,
                                           float& d, float& dc)
{
    float diff = a * (1.0f / 255.0f) - p;
    d = sqrtf(diff * diff + EPS2);
    float om = 1.0f - p;
    float e0 = i0 - (f0 * p + om * g0);
    float e1 = i1 - (f1 * p + om * g1);
    float e2 = i2 - (f2 * p + om * g2);
    dc = sqrtf(e0 * e0 + EPS2) + sqrtf(e1 * e1 + EPS2) + sqrtf(e2 * e2 + EPS2);
}

// Device-scope software grid barrier. Safe without cooperative launch because
// all NBLK blocks are co-resident by construction (512 blocks, 4 blocks/CU cap
// from __launch_bounds__(256,4) => 1024 slots). __threadfence() provides
// release (flush prior plain stores) / acquire (invalidate stale caches)
// semantics across XCDs; arrive/flag ops are device-scope atomics.
__device__ void gridbar(unsigned* __restrict__ bar, int slot)
{
    __syncthreads();                       // all waves drain their stores (vmcnt before s_barrier)
    if (threadIdx.x == 0) {
        __threadfence();                   // release: make prior writes device-visible
        unsigned arrived = atomicAdd(&bar[slot * 2], 1u);
        if (arrived == (unsigned)(NBLK - 1)) {
            atomicAdd(&bar[slot * 2 + 1], 1u);          // set flag
        } else {
            while (atomicAdd(&bar[slot * 2 + 1], 0u) == 0u)  // atomic poll, device scope
                __builtin_amdgcn_s_sleep(8);
        }
        __threadfence();                   // acquire: subsequent plain loads see fresh data
    }
    __syncthreads();
}

// Block-collective selection over a 1024-bin count histogram: find b1 with
// count(bin > b1) < k <= count(bin >= b1); rem = k - count(bin > b1).
__device__ void select_unit(const unsigned* __restrict__ hc, unsigned k,
                            unsigned* sufB, unsigned* bcast, Sel& out)
{
    const int t = threadIdx.x;
    unsigned bins[BPT];
    unsigned pc = 0;
#pragma unroll
    for (int j = 0; j < BPT; ++j) { bins[j] = hc[t * BPT + j]; pc += bins[j]; }
    sufB[t] = pc;
    __syncthreads();
    // inclusive suffix sum (Hillis-Steele; read-sync-write-sync)
    for (int off = 1; off < TPB; off <<= 1) {
        unsigned add = (t + off < TPB) ? sufB[t + off] : 0u;
        __syncthreads();
        sufB[t] += add;
        __syncthreads();
    }
    unsigned suf = sufB[t];
    if (t == 0) { bcast[0] = 0xFFFFFFFFu; bcast[1] = 0u; bcast[2] = 0u; }
    __syncthreads();
    if (k > 0) {
        unsigned above = suf - pc;
        if (above < k && k <= suf) {       // exactly one thread
            unsigned c = above; int b1 = -1;
#pragma unroll
            for (int j = BPT - 1; j >= 0; --j) {
                if (b1 < 0) {
                    if (c + bins[j] >= k) b1 = t * BPT + j;
                    else c += bins[j];
                }
            }
            bcast[0] = (unsigned)b1; bcast[1] = k - c; bcast[2] = k;
        }
    }
    __syncthreads();
    out.b1 = bcast[0]; out.rem = bcast[1]; out.k = bcast[2];
    __syncthreads();   // safe LDS reuse after return
}

__global__ __launch_bounds__(TPB, 4) void k_fused(
    const float* __restrict__ image, const float* __restrict__ alpha,
    const float* __restrict__ pred, const int* __restrict__ trimap,
    const float* __restrict__ fg, const float* __restrict__ bg,
    unsigned* __restrict__ bar, unsigned* __restrict__ gcnt,
    unsigned* __restrict__ h1c, float* __restrict__ hpriv,
    float* __restrict__ sgl, float* __restrict__ out)
{
    __shared__ unsigned hc[2 * NBINS];     // 8KB  level-1 count hist (d, dc)
    __shared__ unsigned scnt[2 * NBINS2];  // 2KB  boundary sub-hist counts
    __shared__ float    ssum[2 * NBINS2];  // 2KB  boundary sub-hist sums
    __shared__ unsigned sufB[TPB];         // 1KB
    __shared__ float    sufF[TPB];         // 1KB
    __shared__ unsigned bcast[4];
    __shared__ float    fred[8];

    const int tid = threadIdx.x;
    const int b = blockIdx.x;
    const int s = b / BPSAMP;
    const int ch = b % BPSAMP;

    for (int i = tid; i < 2 * NBINS; i += TPB) hc[i] = 0u;
    for (int i = tid; i < 2 * NBINS2; i += TPB) { scnt[i] = 0u; ssum[i] = 0.f; }
    __syncthreads();

    // ---------------- Phase 1: stream inputs, values -> registers, LDS count hist ----------------
    const int pbase = s * NPIX + ch * PPB;
    const int cbase = s * 3 * NPIX + ch * PPB;
    float dv[PPT], cv[PPT];
    unsigned unkm = 0;
    unsigned nUnk = 0;

#pragma unroll
    for (int it = 0; it < PPT / 4; ++it) {
        const int off = (it * TPB + tid) * 4;
        int4   tm = *(const int4*)(trimap + pbase + off);
        float4 al = *(const float4*)(alpha + pbase + off);
        float4 pr = *(const float4*)(pred + pbase + off);
        float4 i0 = *(const float4*)(image + cbase + off);
        float4 i1 = *(const float4*)(image + cbase + NPIX + off);
        float4 i2 = *(const float4*)(image + cbase + 2 * NPIX + off);
        float4 f0 = *(const float4*)(fg + cbase + off);
        float4 f1 = *(const float4*)(fg + cbase + NPIX + off);
        float4 f2 = *(const float4*)(fg + cbase + 2 * NPIX + off);
        float4 g0 = *(const float4*)(bg + cbase + off);
        float4 g1 = *(const float4*)(bg + cbase + NPIX + off);
        float4 g2 = *(const float4*)(bg + cbase + 2 * NPIX + off);
#pragma unroll
        for (int j = 0; j < 4; ++j) {
            const int vi = it * 4 + j;
            float d = 0.f, c = 0.f;
            if (I4E(tm, j) == 128) {
                ++nUnk;
                unkm |= 1u << vi;
                pixel_vals(F4E(al, j), F4E(pr, j),
                           F4E(i0, j), F4E(i1, j), F4E(i2, j),
                           F4E(f0, j), F4E(f1, j), F4E(f2, j),
                           F4E(g0, j), F4E(g1, j), F4E(g2, j), d, c);
                atomicAdd(&hc[__float_as_uint(d) >> 21], 1u);           // plain LDS atomics
                atomicAdd(&hc[NBINS + (__float_as_uint(c) >> 21)], 1u); // (masked excluded: k < unknown count,
            }                                                            //  masked value = global min => same top-k sum)
            dv[vi] = d; cv[vi] = c;
        }
    }

    // per-sample unknown count
    unsigned u = nUnk;
#pragma unroll
    for (int o = 32; o > 0; o >>= 1) u += __shfl_down(u, o);
    if ((tid & 63) == 0) sufB[tid >> 6] = u;
    __syncthreads();
    if (tid == 0) atomicAdd(&gcnt[s], sufB[0] + sufB[1] + sufB[2] + sufB[3]);
    __syncthreads();

    // flush LDS hist -> global (only nonzero bins; device-scope atomics)
    for (int i = tid; i < 2 * NBINS; i += TPB) {
        unsigned cc = hc[i];
        if (cc) atomicAdd(&h1c[(s * 2 + (i >= NBINS ? 1 : 0)) * NBINS + (i & (NBINS - 1))], cc);
    }

    gridbar(bar, 0);

    // ---------------- Phase 2: per-block redundant selection for its sample's 2 units ----------------
    unsigned K = gcnt[s];
    unsigned kk = (unsigned)(int)floorf((float)K * 0.7f);
    Sel Sd, Sc;
    select_unit(h1c + (s * 2 + 0) * NBINS, kk, sufB, bcast, Sd);
    select_unit(h1c + (s * 2 + 1) * NBINS, kk, sufB, bcast, Sc);

    // ---------------- Phase 3: register re-scan: sum above b1 + boundary sub-hist ----------------
    float lsd = 0.f, lsc = 0.f;
#pragma unroll
    for (int vi = 0; vi < PPT; ++vi) {
        if (unkm & (1u << vi)) {
            unsigned bits = __float_as_uint(dv[vi]);
            unsigned bd = bits >> 21;
            if (Sd.b1 != 0xFFFFFFFFu) {
                if (bd > Sd.b1) lsd += dv[vi];
                else if (bd == Sd.b1) {
                    unsigned sb = (bits >> 13) & (NBINS2 - 1);
                    atomicAdd(&scnt[sb], 1u);
                    atomicAdd(&ssum[sb], dv[vi]);
                }
            }
            unsigned cbits = __float_as_uint(cv[vi]);
            unsigned bc = cbits >> 21;
            if (Sc.b1 != 0xFFFFFFFFu) {
                if (bc > Sc.b1) lsc += cv[vi];
                else if (bc == Sc.b1) {
                    unsigned sb = (cbits >> 13) & (NBINS2 - 1);
                    atomicAdd(&scnt[NBINS2 + sb], 1u);
                    atomicAdd(&ssum[NBINS2 + sb], cv[vi]);
                }
            }
        }
    }
#pragma unroll
    for (int o = 32; o > 0; o >>= 1) { lsd += __shfl_down(lsd, o); lsc += __shfl_down(lsc, o); }
    if ((tid & 63) == 0) { fred[tid >> 6] = lsd; fred[4 + (tid >> 6)] = lsc; }
    __syncthreads();   // also orders sub-hist LDS atomics before flush
    if (tid == 0) {
        sgl[(size_t)(s * BPSAMP + ch) * 2 + 0] = fred[0] + fred[1] + fred[2] + fred[3];
        sgl[(size_t)(s * BPSAMP + ch) * 2 + 1] = fred[4] + fred[5] + fred[6] + fred[7];
    }
    // private sub-hist store (plain stores; made visible by gridbar's release fence)
    {
        float* hp = hpriv + (size_t)(s * BPSAMP + ch) * (4 * NBINS2);
        hp[0 * NBINS2 + tid] = (float)scnt[tid];
        hp[1 * NBINS2 + tid] = ssum[tid];
        hp[2 * NBINS2 + tid] = (float)scnt[NBINS2 + tid];
        hp[3 * NBINS2 + tid] = ssum[NBINS2 + tid];
    }

    gridbar(bar, 1);

    // ---------------- Phase 4: 16 blocks finalize (block b = unit) ----------------
    if (b < 2 * NB) {
        const int uu = b, ss = uu >> 1, arr = uu & 1;
        unsigned K2 = gcnt[ss];
        unsigned kk2 = (unsigned)(int)floorf((float)K2 * 0.7f);
        Sel S;
        select_unit(h1c + uu * NBINS, kk2, sufB, bcast, S);
        if (S.b1 != 0xFFFFFFFFu) {
            // gather 64 private sub-hists: thread t owns sub-bin t
            float cc = 0.f, sm = 0.f;
            for (int c2 = 0; c2 < BPSAMP; ++c2) {
                const float* hp = hpriv + (size_t)(ss * BPSAMP + c2) * (4 * NBINS2) + arr * 2 * NBINS2;
                cc += hp[tid];
                sm += hp[NBINS2 + tid];
            }
            // total sum above b1
            sufF[tid] = (tid < BPSAMP) ? sgl[(size_t)(ss * BPSAMP + tid) * 2 + arr] : 0.f;
            __syncthreads();
            for (int off = TPB / 2; off > 0; off >>= 1) {
                if (tid < off) sufF[tid] += sufF[tid + off];
                __syncthreads();
            }
            float Ltot = sufF[0];
            __syncthreads();
            // joint suffix scans of counts and sums over 256 sub-bins
            unsigned myc = (unsigned)cc;
            sufB[tid] = myc; sufF[tid] = sm;
            __syncthreads();
            for (int off = 1; off < TPB; off <<= 1) {
                unsigned ac = (tid + off < TPB) ? sufB[tid + off] : 0u;
                float    as = (tid + off < TPB) ? sufF[tid + off] : 0.f;
                __syncthreads();
                sufB[tid] += ac; sufF[tid] += as;
                __syncthreads();
            }
            unsigned suf = sufB[tid];
            unsigned above = suf - myc;
            if (above < S.rem && S.rem <= suf) {   // exactly one thread
                unsigned rem2 = S.rem - above;
                float avg = sm / (float)myc;       // myc >= rem2 >= 1
                float sum_k = Ltot + (sufF[tid] - sm) + (float)rem2 * avg;
                float loss = sum_k / ((float)S.k + 1e-6f);
                atomicAdd(out, 0.0625f * loss);    // 0.5 stage weight / 8 samples, both arrays
            }
        }
    }
}

extern "C" void kernel_launch(void* const* d_in, const int* in_sizes, int n_in,
                              void* d_out, int out_size, void* d_ws, size_t ws_size,
                              hipStream_t stream)
{
    const float* image  = (const float*)d_in[0];
    const float* alpha  = (const float*)d_in[1];
    const float* pred   = (const float*)d_in[2];
    const int*   trimap = (const int*)d_in[3];
    const float* fg     = (const float*)d_in[4];
    const float* bg     = (const float*)d_in[5];
    float* out = (float*)d_out;

    char* ws = (char*)d_ws;
    // layout: bar[4] (64B) | gcnt[8] (64B) | h1c 64KB | sgl 4KB | pad | hpriv 2MB
    unsigned* bar   = (unsigned*)(ws);
    unsigned* gcnt  = (unsigned*)(ws + 64);
    unsigned* h1c   = (unsigned*)(ws + 128);
    float*    sgl   = (float*)(ws + 128 + 65536);
    float*    hpriv = (float*)(ws + 131072);
    const size_t zbytes = 128 + 65536;   // bar + gcnt + h1c (sgl/hpriv fully overwritten before read)

    hipMemsetAsync(d_ws, 0, zbytes, stream);
    hipMemsetAsync(d_out, 0, sizeof(float), stream);
    k_fused<<<NBLK, TPB, 0, stream>>>(image, alpha, pred, trimap, fg, bg,
                                      bar, gcnt, h1c, hpriv, sgl, out);
}